// Round 11
// baseline (334.315 us; speedup 1.0000x reference)
//
#include <hip/hip_runtime.h>
#include <cstdint>
#include <cstddef>

// SelfAttention: B=8, S=2048, D=512, fp32 in/out.
// R10: TLP rework. R9's counters: MFMA pipe ~5%, LDS ~30%, VALU 26%, ~40%
// barrier/latency idle at 1 block/CU. Fix: halve the block (32 Q-rows, KT=32)
// -> LDS 68.9 KB -> 2 blocks/CU (512 blocks) so phases of co-resident blocks
// overlap. Phase A: 4 waves x one 16x16 quadrant of S^T (swapped operands,
// K as A), 2 indep MFMA chains. acc halves to 64 VGPRs (peak ~170, no spill
// risk). R9's barrier/pipeline skeleton + defer-max kept unchanged.
// ws: [qh 16M][kh 16M][vh 16M][vt 16M (xh aliases)][Wt 1.5M] = 65.5 MiB.

#define SEQ 2048
#define DIM 512
#define NB 8
#define BSZ (NB * SEQ)
#define KT 32
#define NT (SEQ / KT)
#define QROWS 32

typedef __attribute__((ext_vector_type(8))) _Float16 half8;
typedef __attribute__((ext_vector_type(2))) __fp16 fp16x2;
typedef __attribute__((ext_vector_type(4))) float f32x4;

__device__ __forceinline__ unsigned short f2h(float f) {
  _Float16 h = (_Float16)f;
  return __builtin_bit_cast(unsigned short, h);
}
__device__ __forceinline__ half8 ld_frag(const unsigned short* p) {
  return *(const half8*)(const void*)p;
}
__device__ __forceinline__ void gl_lds16(const unsigned short* g, unsigned short* l) {
  __builtin_amdgcn_global_load_lds(
      (__attribute__((address_space(1))) void*)g,
      (__attribute__((address_space(3))) void*)l, 16, 0, 0);
}
// Fused waitcnt+barrier (single asm block: nothing schedules between them).
__device__ __forceinline__ void bar_vm0() {
  asm volatile("s_waitcnt vmcnt(0)\ns_barrier" ::: "memory");
}
__device__ __forceinline__ void bar_lgkm() {
  asm volatile("s_waitcnt lgkmcnt(0)\ns_barrier" ::: "memory");
}
__device__ __forceinline__ void bar_lgkm_vm0() {
  asm volatile("s_waitcnt lgkmcnt(0) vmcnt(0)\ns_barrier" ::: "memory");
}

// ---------------------------------------------------------------------------
__global__ __launch_bounds__(256) void cvt_x_kernel(
    const float* __restrict__ X, unsigned short* __restrict__ xh)
{
  size_t i0 = ((size_t)blockIdx.x * 256 + threadIdx.x) * 8;
  float4 a = *(const float4*)&X[i0];
  float4 b = *(const float4*)&X[i0 + 4];
  ushort4 o0; o0.x = f2h(a.x); o0.y = f2h(a.y); o0.z = f2h(a.z); o0.w = f2h(a.w);
  ushort4 o1; o1.x = f2h(b.x); o1.y = f2h(b.y); o1.z = f2h(b.z); o1.w = f2h(b.w);
  *(ushort4*)&xh[i0] = o0;
  *(ushort4*)&xh[i0 + 4] = o1;
}

// ---------------------------------------------------------------------------
__global__ __launch_bounds__(256) void cvt_w_kernel(
    const float* __restrict__ Wq, const float* __restrict__ Wk,
    const float* __restrict__ Wv, unsigned short* __restrict__ Wt)
{
  const int z = blockIdx.z;
  const float* W = (z == 0) ? Wq : (z == 1) ? Wk : Wv;
  unsigned short* out = Wt + (size_t)z * DIM * DIM;
  const int k0 = blockIdx.x * 64, n0 = blockIdx.y * 64;
  const int t = threadIdx.x;
  __shared__ unsigned short tl[64 * 72];
#pragma unroll
  for (int i = 0; i < 4; i++) {
    int f = t + 256 * i;
    int kr = f >> 4, c4 = (f & 15) * 4;
    float4 v = *(const float4*)&W[(size_t)(k0 + kr) * DIM + n0 + c4];
    tl[(c4 + 0) * 72 + kr] = f2h(v.x);
    tl[(c4 + 1) * 72 + kr] = f2h(v.y);
    tl[(c4 + 2) * 72 + kr] = f2h(v.z);
    tl[(c4 + 3) * 72 + kr] = f2h(v.w);
  }
  __syncthreads();
#pragma unroll
  for (int i = 0; i < 2; i++) {
    int f = t + 256 * i;
    int nr = f >> 3, k8 = (f & 7) * 8;
    *(uint4*)&out[(size_t)(n0 + nr) * DIM + k0 + k8] = *(const uint4*)&tl[nr * 72 + k8];
  }
}

// ---------------------------------------------------------------------------
// proj (unchanged): qkv[z] = fp16(xh @ Wt[z]^T + b[z]).
// ---------------------------------------------------------------------------
__global__ __launch_bounds__(256) void proj_kernel(
    const unsigned short* __restrict__ xh, const unsigned short* __restrict__ Wt,
    const float* __restrict__ bq, const float* __restrict__ bk,
    const float* __restrict__ bv, unsigned short* __restrict__ outbase)
{
  const int z = blockIdx.z;
  const unsigned short* Wz = Wt + (size_t)z * DIM * DIM;
  const float* bias = (z == 0) ? bq : (z == 1) ? bk : bv;
  unsigned short* out = outbase + (size_t)z * BSZ * DIM;
  const int m0 = blockIdx.x * 128, n0 = blockIdx.y * 128;
  const int t = threadIdx.x, lane = t & 63, wave = t >> 6;
  const int wrow = (wave >> 1) * 64, wcol = (wave & 1) * 64;
  const int lr = lane & 15, lq = (lane >> 4) * 8;

  __shared__ unsigned short sm[128 * 132];
  unsigned short* As = sm;
  unsigned short* Bs = sm + 128 * 64;

  f32x4 acc[4][4];
  const f32x4 zero = {0.f, 0.f, 0.f, 0.f};
#pragma unroll
  for (int r = 0; r < 4; r++)
#pragma unroll
    for (int c = 0; c < 4; c++) acc[r][c] = zero;

  for (int k0 = 0; k0 < DIM; k0 += 64) {
    __syncthreads();
#pragma unroll
    for (int i = 0; i < 4; i++) {
      int f = t + 256 * i;
      int row = f >> 3, c8 = (f & 7) * 8;
      gl_lds16(&xh[(size_t)(m0 + row) * DIM + k0 + c8], &As[i * 2048 + wave * 512]);
      gl_lds16(&Wz[(size_t)(n0 + row) * DIM + k0 + c8], &Bs[i * 2048 + wave * 512]);
    }
    __syncthreads();
#pragma unroll
    for (int kk = 0; kk < 64; kk += 32) {
      half8 a[4], b[4];
#pragma unroll
      for (int r = 0; r < 4; r++) a[r] = ld_frag(&As[(wrow + 16 * r + lr) * 64 + kk + lq]);
#pragma unroll
      for (int c = 0; c < 4; c++) b[c] = ld_frag(&Bs[(wcol + 16 * c + lr) * 64 + kk + lq]);
#pragma unroll
      for (int r = 0; r < 4; r++)
#pragma unroll
        for (int c = 0; c < 4; c++)
          acc[r][c] = __builtin_amdgcn_mfma_f32_16x16x32_f16(a[r], b[c], acc[r][c], 0, 0, 0);
    }
  }
  __syncthreads();
#pragma unroll
  for (int c = 0; c < 4; c++) {
    float bb = bias[n0 + wcol + 16 * c + lr];
#pragma unroll
    for (int r = 0; r < 4; r++)
#pragma unroll
      for (int e = 0; e < 4; e++)
        sm[(wrow + 16 * r + (lane >> 4) * 4 + e) * 132 + wcol + 16 * c + lr] =
            f2h(acc[r][c][e] + bb);
  }
  __syncthreads();
#pragma unroll
  for (int i = 0; i < 8; i++) {
    int f = t + 256 * i;
    int row = f >> 4, c8 = (f & 15) * 8;
    *(uint4*)&out[(size_t)(m0 + row) * DIM + n0 + c8] = *(const uint4*)&sm[row * 132 + c8];
  }
}

// ---------------------------------------------------------------------------
__global__ __launch_bounds__(256) void vtrans_kernel(
    const unsigned short* __restrict__ vh, unsigned short* __restrict__ vt)
{
  const int b = blockIdx.z;
  const int s0 = blockIdx.x * 64, n0 = blockIdx.y * 64;
  const int t = threadIdx.x;
  __shared__ unsigned short tl[64 * 72];
#pragma unroll
  for (int i = 0; i < 2; i++) {
    int f = t + 256 * i;
    int sr = f >> 3, c8 = (f & 7) * 8;
    uint4 raw = *(const uint4*)&vh[((size_t)b * SEQ + s0 + sr) * DIM + n0 + c8];
    unsigned short u[8];
    *(uint4*)u = raw;
#pragma unroll
    for (int j = 0; j < 8; j++) tl[(c8 + j) * 72 + sr] = u[j];
  }
  __syncthreads();
#pragma unroll
  for (int i = 0; i < 2; i++) {
    int f = t + 256 * i;
    int nr = f >> 3, s8 = (f & 7) * 8;
    *(uint4*)&vt[((size_t)b * DIM + n0 + nr) * SEQ + s0 + s8] = *(const uint4*)&tl[nr * 72 + s8];
  }
}

// ---------------------------------------------------------------------------
// flash R10. Block = 32 Q rows, 4 waves: (kq = wave&1, rq = wave>>1).
// Wave owns S^T quadrant [keys kq*16..+16][qrows rq*16..+16] in phase A
// (16x16x32, swapped: A=K from LDS, B=Q from LDS; key=(lane>>4)*4+e,
// qrow=lane&15) and d-slice [wave*128..+128] x 32 rows in phase C.
// Per kt: top bar_vm0 -> vf loads -> A (2 chains x 8 MFMA) -> max: in-lane 4
// + xor16 + xor32 + kq-pair via mpart; bar#1 -> K(kt+1) -> defer-max, P b64
// writes, lpart; bar#2 -> lrun, uniform-skip rescale, pf -> C (16 MFMA).
// LDS 68.9 KB -> 2 blocks/CU. Grid 512.
// ---------------------------------------------------------------------------
#define PSTR 40   // Pbuf row stride (halves) = 80B: rows 16B-aligned
#define OSTR 516  // Obuf row stride (floats)

__global__ __launch_bounds__(256, 2) void flash_kernel(
    const unsigned short* __restrict__ Qb, const unsigned short* __restrict__ Kb,
    const unsigned short* __restrict__ Vtb, float* __restrict__ Ob)
{
  const int zb = blockIdx.x & 7;              // batch -> XCD affinity
  const int q0 = (blockIdx.x >> 3) * QROWS;   // q-tile base row
  const unsigned short* Q = Qb + (size_t)zb * SEQ * DIM;
  const unsigned short* K = Kb + (size_t)zb * SEQ * DIM;
  const unsigned short* V = Vtb + (size_t)zb * DIM * SEQ;  // [d][s]
  float* Out = Ob + (size_t)zb * SEQ * DIM;

  const int t = threadIdx.x, lane = t & 63, wave = t >> 6;
  const int kq = wave & 1, rq = wave >> 1;
  const int lr = lane & 15, lq4 = lane >> 4;
  const float L2E = 1.4426950408889634f;

  // LDS carve (halves): Qbuf 16384 | Kbuf 16384 | Pbuf 32*40=1280 |
  // mpart 128 | lpart 128 | abuf 64 | lrun 64 | fbuf 16 = 34448 h = 68.9 KB.
  __shared__ unsigned short lds[34448];
  unsigned short* Qbuf = lds;              // [32 rows][512], swizzled
  unsigned short* Kbuf = lds + 16384;      // [32 keys][512], swizzled
  unsigned short* Pbuf = lds + 32768;      // [32 qrows][PSTR]
  float* mpart = (float*)(lds + 34048);    // [2 kq][32 qrows]
  float* lpart = (float*)(lds + 34176);    // [2 kq][32 qrows]
  float* abuf  = (float*)(lds + 34304);    // [32 qrows]
  float* lrun  = (float*)(lds + 34368);    // [32 qrows]
  unsigned int* fbuf = (unsigned int*)(lds + 34432);  // [4] keep flags

  if (t < 32) lrun[t] = 0.f;

  // staging offsets: tile [32 rows][512 halves], 64 chunks/row of 8h,
  // source chunk = lds chunk ^ (row&7). instr i: row = 4i+wave, c = lane.
  int koff[8];
#pragma unroll
  for (int i = 0; i < 8; i++) {
    int f = t + 256 * i;
    int row = f >> 6, c = f & 63;
    koff[i] = row * DIM + (c ^ (row & 7)) * 8;
  }

  // ---- stage Q -> Qbuf (resident), K(0) -> Kbuf; drained at loop-top bar ----
#pragma unroll
  for (int i = 0; i < 8; i++)
    gl_lds16(&Q[(size_t)q0 * DIM + koff[i]], &Qbuf[i * 2048 + wave * 512]);
#pragma unroll
  for (int i = 0; i < 8; i++)
    gl_lds16(&K[koff[i]], &Kbuf[i * 2048 + wave * 512]);

  // ---- running state ----
  f32x4 acc[16];  // [rg 0..1][dc 0..7]: row rg*16+lq4*4+e, d wave*128+dc*16+lr
  const f32x4 zero = {0.f, 0.f, 0.f, 0.f};
#pragma unroll
  for (int ob = 0; ob < 16; ob++) acc[ob] = zero;
  float m_run = -__builtin_inff();  // per lane: qrow rq*16 + lr

  const int keyrow = kq * 16 + lr, ksw = keyrow & 7;
  const int qrow = rq * 16 + lr, qsw = qrow & 7;
  const unsigned short* Kc = Kbuf + keyrow * 512;
  const unsigned short* Qc = Qbuf + qrow * 512;

  for (int kt = 0; kt < NT; kt++) {
    bar_vm0();  // K(kt) (and Q at kt=0) landed for all waves

    // ---- vf: wave's d-slice V^T B-frags (8 x 16B global, covered by A+B) ----
    const unsigned short* Vb = V + (size_t)(wave * 128 + lr) * SEQ + kt * KT + lq4 * 8;
    half8 vf[8];
#pragma unroll
    for (int dc = 0; dc < 8; dc++)
      vf[dc] = ld_frag(Vb + (size_t)dc * 16 * SEQ);

    // ===== phase A: S^T quadrant = K·Q^T, 2 chains (k 0..255 / 256..511) =====
    f32x4 s0 = zero, s1 = zero;
    __builtin_amdgcn_s_setprio(1);
#pragma unroll
    for (int j = 0; j < 8; j++) {
      half8 kf0 = ld_frag(&Kc[(((4 * j + lq4) ^ ksw) << 3)]);
      half8 qv0 = ld_frag(&Qc[(((4 * j + lq4) ^ qsw) << 3)]);
      half8 kf1 = ld_frag(&Kc[(((4 * (j + 8) + lq4) ^ ksw) << 3)]);
      half8 qv1 = ld_frag(&Qc[(((4 * (j + 8) + lq4) ^ qsw) << 3)]);
      s0 = __builtin_amdgcn_mfma_f32_16x16x32_f16(kf0, qv0, s0, 0, 0, 0);
      s1 = __builtin_amdgcn_mfma_f32_16x16x32_f16(kf1, qv1, s1, 0, 0, 0);
    }
    __builtin_amdgcn_s_setprio(0);
    f32x4 sacc = s0 + s1;
    // lane holds keys kq*16 + lq4*4 + {0..3} for qrow rq*16 + lr.

    // ===== phase B: defer-max online softmax =====
    float mx = fmaxf(fmaxf(sacc[0], sacc[1]), fmaxf(sacc[2], sacc[3]));
    mx = fmaxf(mx, __shfl_xor(mx, 16, 64));
    mx = fmaxf(mx, __shfl_xor(mx, 32, 64));
    if (lane < 16) mpart[kq * 32 + rq * 16 + lane] = mx;
    bar_lgkm();  // #1: mpart visible; ALL phase-A ds_reads drained block-wide

    // issue K(kt+1) into same Kbuf (A-reads done)
    if (kt + 1 < NT) {
      const unsigned short* Kt = K + (size_t)(kt + 1) * KT * DIM;
#pragma unroll
      for (int i = 0; i < 8; i++)
        gl_lds16(&Kt[koff[i]], &Kbuf[i * 2048 + wave * 512]);
    }

    float mo = mpart[(kq ^ 1) * 32 + rq * 16 + lr];
    float mxc = fmaxf(mx, mo);
    // defer-max: keep m_run when growth <= 8 (P bounded by e^8 < f16 max)
    bool keep = (mxc - m_run <= 8.0f);
    float mnew = keep ? m_run : mxc;
    float alpha = keep ? 1.0f : exp2f((m_run - mnew) * L2E);
    m_run = mnew;
    if (kq == 0 && lane < 16) abuf[rq * 16 + lane] = alpha;
    unsigned long long ball = __ballot(keep);
    if (lane == 0) fbuf[wave] = (ball == ~0ull) ? 1u : 0u;

    // P = exp(S - m): 4 keys -> one b64 write (16B-aligned rows, PSTR=40)
    float p0 = exp2f((sacc[0] - mnew) * L2E);
    float p1 = exp2f((sacc[1] - mnew) * L2E);
    float p2 = exp2f((sacc[2] - mnew) * L2E);
    float p3 = exp2f((sacc[3] - mnew) * L2E);
    float psum = (p0 + p1) + (p2 + p3);
    {
      fp16x2 pa = __builtin_amdgcn_cvt_pkrtz(p0, p1);
      fp16x2 pb = __builtin_amdgcn_cvt_pkrtz(p2, p3);
      unsigned long long both =
          ((unsigned long long)__builtin_bit_cast(unsigned int, pb) << 32) |
          __builtin_bit_cast(unsigned int, pa);
      *(unsigned long long*)&Pbuf[qrow * PSTR + kq * 16 + lq4 * 4] = both;
    }
    psum += __shfl_xor(psum, 16, 64);
    psum += __shfl_xor(psum, 32, 64);
    if (lane < 16) lpart[kq * 32 + rq * 16 + lane] = psum;
    bar_lgkm();  // #2: Pbuf, abuf, lpart, fbuf visible
    if (kq == 0 && lane < 16) {
      int r = rq * 16 + lane;
      lrun[r] = alpha * lrun[r] + lpart[r] + lpart[32 + r];
    }

    // ---- rescale acc only when some row moved its max (block-uniform) ----
    if (!(fbuf[0] & fbuf[1] & fbuf[2] & fbuf[3])) {
#pragma unroll
      for (int rg = 0; rg < 2; rg++)
#pragma unroll
        for (int e = 0; e < 4; e++) {
          float a = abuf[rg * 16 + lq4 * 4 + e];
#pragma unroll
          for (int dc = 0; dc < 8; dc++) acc[rg * 8 + dc][e] *= a;
        }
    }

    // ===== phase C: O += P V (wave: all 32 rows x its 128-d slice) =====
    half8 pf[2];
#pragma unroll
    for (int rg = 0; rg < 2; rg++)
      pf[rg] = ld_frag(&Pbuf[(rg * 16 + lr) * PSTR + lq4 * 8]);
    __builtin_amdgcn_s_setprio(1);
#pragma unroll
    for (int dc = 0; dc < 8; dc++)
#pragma unroll
      for (int rg = 0; rg < 2; rg++)
        acc[rg * 8 + dc] =
            __builtin_amdgcn_mfma_f32_16x16x32_f16(pf[rg], vf[dc], acc[rg * 8 + dc], 0, 0, 0);
    __builtin_amdgcn_s_setprio(0);
  }

  bar_lgkm_vm0();  // lrun final, all LDS quiesced before Obuf reuse

  // ---- finalize: O /= l, repack via LDS, coalesced stores ----
  float linv[2][4];
#pragma unroll
  for (int rg = 0; rg < 2; rg++)
#pragma unroll
    for (int e = 0; e < 4; e++) linv[rg][e] = 1.0f / lrun[rg * 16 + lq4 * 4 + e];

  float* Obuf = (float*)lds;  // 32 x OSTR floats = 66 KB over Qbuf/Kbuf/Pbuf
#pragma unroll
  for (int rg = 0; rg < 2; rg++)
#pragma unroll
    for (int e = 0; e < 4; e++) {
      int row = rg * 16 + lq4 * 4 + e;
#pragma unroll
      for (int dc = 0; dc < 8; dc++)
        Obuf[row * OSTR + wave * 128 + dc * 16 + lr] = acc[rg * 8 + dc][e] * linv[rg][e];
    }
  __syncthreads();
#pragma unroll
  for (int i = 0; i < 16; i++) {
    int f = t + 256 * i;
    int row = f >> 7, c4 = (f & 127) * 4;
    *(float4*)&Out[(size_t)(q0 + row) * DIM + c4] = *(const float4*)&Obuf[row * OSTR + c4];
  }
}

// ---------------------------------------------------------------------------
extern "C" void kernel_launch(void* const* d_in, const int* in_sizes, int n_in,
                              void* d_out, int out_size, void* d_ws, size_t ws_size,
                              hipStream_t stream)
{
  const float* X  = (const float*)d_in[0];
  const float* Wq = (const float*)d_in[1];
  const float* bq = (const float*)d_in[2];
  const float* Wk = (const float*)d_in[3];
  const float* bk = (const float*)d_in[4];
  const float* Wv = (const float*)d_in[5];
  const float* bv = (const float*)d_in[6];
  float* Out = (float*)d_out;

  char* ws = (char*)d_ws;
  const size_t MB = 1u << 20;
  unsigned short* qh = (unsigned short*)(ws);            // 16 MiB
  unsigned short* kh = (unsigned short*)(ws + 16 * MB);  // 16 MiB (proj z=1)
  unsigned short* vh = (unsigned short*)(ws + 32 * MB);  // 16 MiB (proj z=2)
  unsigned short* vt = (unsigned short*)(ws + 48 * MB);  // 16 MiB
  unsigned short* xh = (unsigned short*)(ws + 48 * MB);  // alias vt: dead pre-vtrans
  unsigned short* Wt = (unsigned short*)(ws + 64 * MB);  // 1.5 MiB

  cvt_x_kernel<<<dim3(BSZ * DIM / 2048), 256, 0, stream>>>(X, xh);
  cvt_w_kernel<<<dim3(8, 8, 3), 256, 0, stream>>>(Wq, Wk, Wv, Wt);
  proj_kernel<<<dim3(BSZ / 128, DIM / 128, 3), 256, 0, stream>>>(
      xh, Wt, bq, bk, bv, qh);
  vtrans_kernel<<<dim3(SEQ / 64, DIM / 64, NB), 256, 0, stream>>>(vh, vt);
  flash_kernel<<<dim3(NB * SEQ / QROWS), 256, 0, stream>>>(qh, kh, vt, Out);
}